// Round 1
// baseline (297.711 us; speedup 1.0000x reference)
//
#include <hip/hip_runtime.h>
#include <hip/hip_bf16.h>
#include <stdint.h>

// y[c,k] = sum_{a,b} E1[k,a] * Xc[c,a,b] * E2[k,b],  Xc = C*x, E = exp(i*angle*g)
// Stage 1 (MFMA): tmp[a, 2k+comp] = A'[a,:] @ B'[:, 2k+comp]
//   A' = [Re(Xc) | Im(Xc)]  (256 x 512)
//   B'[b,2k]=Er, B'[256+b,2k]=-Ei, B'[b,2k+1]=Ei, B'[256+b,2k+1]=Er
// Stage 2 (epilogue): y[c,k] = sum_a E1[k,a] (*) tmp[a,k]  (complex), * w[k%512]
//
// R2 restructure:
//  - B tile double-buffered in LDS; stage(t+1) issued BEFORE compute(t), single
//    __syncthreads() after compute. The vmcnt(0) drain at the barrier then
//    happens ~64 MFMAs after load issue -> latency hidden (T3-minimum 2-phase).
//  - A fragments loaded DIRECTly from global (L2/L3-hot, 2MB total): per wave
//    each load instr touches 16 rows x 64 contiguous bytes = 16 full lines.
//    Removes 2/3 of staging loads and 1/3 of ds_read_b128 (LDS pipe was near
//    critical), and shrinks LDS 50KB -> 34KB so 3 blocks/CU fit.
//  - Bs keeps the chunk-XOR swizzle (slot = chunk ^ (row&7)): fragment
//    ds_read_b128s stay perfectly bank-balanced (conflicts were 0, keep it).

#define NKTOT 17408
#define NBLK_K 272   // 17408 / 64
#define LDA 512
#define LDBT 512

typedef short bf16x8 __attribute__((ext_vector_type(8)));
typedef float f32x4 __attribute__((ext_vector_type(4)));

__device__ __forceinline__ unsigned short f2bf(float f) {
  unsigned int u = __builtin_bit_cast(unsigned int, f);
  u += 0x7FFFu + ((u >> 16) & 1u);
  return (unsigned short)(u >> 16);
}
__device__ __forceinline__ float bf2f(unsigned int lo16) {
  return __builtin_bit_cast(float, lo16 << 16);
}

__device__ __forceinline__ void async_copy16(void* lds, const void* g) {
  __builtin_amdgcn_global_load_lds(
      (const __attribute__((address_space(1))) unsigned int*)g,
      (__attribute__((address_space(3))) unsigned int*)lds, 16, 0, 0);
}

__global__ __launch_bounds__(256) void pack_a(
    const float* __restrict__ input_r, const float* __restrict__ C_r,
    unsigned short* __restrict__ Apack)
{
  int tid = blockIdx.x * 256 + threadIdx.x;  // 0 .. 8*256*256-1
  int b = tid & 255;
  int a = (tid >> 8) & 255;
  int c = tid >> 16;
  float xr = input_r[(a * 256 + b) * 2 + 0];
  float xi = input_r[(a * 256 + b) * 2 + 1];
  size_t ci0 = ((size_t)(c * 256 + a) * 256 + b) * 2;
  float cr = C_r[ci0 + 0];
  float ci = C_r[ci0 + 1];
  float re = cr * xr - ci * xi;
  float im = cr * xi + ci * xr;
  size_t base = (size_t)c * (256 * LDA) + (size_t)a * LDA;
  Apack[base + b] = f2bf(re);
  Apack[base + 256 + b] = f2bf(im);
}

// 4 k per block, 64 lanes per k, 4 consecutive b per lane -> 8B/16B wide stores
// (was: 1 k per 256-thread block, four 2B scattered stores per thread).
__global__ __launch_bounds__(256) void pack_be(
    const float* __restrict__ angle,
    unsigned short* __restrict__ BT, unsigned int* __restrict__ E1tab)
{
  int tid = threadIdx.x;
  int k = blockIdx.x * 4 + (tid >> 6);   // 0..17407
  int b0 = (tid & 63) * 4;               // 0,4,..,252
  float s = angle[k * 2 + 0];
  float t = angle[k * 2 + 1];
  unsigned short c2[4], s2[4], c1[4], s1[4];
#pragma unroll
  for (int j = 0; j < 4; ++j) {
    float g = (float)(b0 + j - 128);
    float sn, cs;
    __sincosf(t * g, &sn, &cs);
    c2[j] = f2bf(cs);
    s2[j] = f2bf(sn);
    __sincosf(s * g, &sn, &cs);
    c1[j] = f2bf(cs);
    s1[j] = f2bf(sn);
  }
  size_t r0 = (size_t)(2 * k) * LDBT;
  ushort4 v;
  v = make_ushort4(c2[0], c2[1], c2[2], c2[3]);
  *(ushort4*)&BT[r0 + b0] = v;
  v = make_ushort4((unsigned short)(s2[0] ^ 0x8000u), (unsigned short)(s2[1] ^ 0x8000u),
                   (unsigned short)(s2[2] ^ 0x8000u), (unsigned short)(s2[3] ^ 0x8000u));
  *(ushort4*)&BT[r0 + 256 + b0] = v;
  v = make_ushort4(s2[0], s2[1], s2[2], s2[3]);
  *(ushort4*)&BT[r0 + LDBT + b0] = v;
  v = make_ushort4(c2[0], c2[1], c2[2], c2[3]);
  *(ushort4*)&BT[r0 + LDBT + 256 + b0] = v;
  uint4 e;
  e.x = (unsigned int)c1[0] | ((unsigned int)s1[0] << 16);
  e.y = (unsigned int)c1[1] | ((unsigned int)s1[1] << 16);
  e.z = (unsigned int)c1[2] | ((unsigned int)s1[2] << 16);
  e.w = (unsigned int)c1[3] | ((unsigned int)s1[3] << 16);
  *(uint4*)&E1tab[k * 256 + b0] = e;
}

__global__ __launch_bounds__(256, 3) void gemm_fused(
    const unsigned short* __restrict__ Apack,
    const unsigned short* __restrict__ BT,
    const unsigned int* __restrict__ E1tab,
    const float* __restrict__ wvec,
    float* __restrict__ out)
{
  __shared__ unsigned short Bs[2][128 * 64];  // 2 x 16 KB, double-buffered
  __shared__ float wavecol[4][128];

  // XCD-aware decode: bx%8 == kt%8 keeps all 8 c-blocks of one kt on the same
  // XCD so its L2 serves B/E1 tiles once.
  const int bx = blockIdx.x;
  const int c = (bx >> 3) & 7;
  const int kt = (bx >> 6) * 8 + (bx & 7);
  const int kt0 = kt * 64;
  const int tid = threadIdx.x;
  const int w = tid >> 6;
  const int l = tid & 63;
  const int lhi = l >> 4;   // 0..3
  const int llo = l & 15;
  const int lr = l >> 3;                       // staging: row within 8-row chunk
  const int lcs = ((l & 7) ^ (l >> 3)) * 8;    // staging: swizzled source chunk

  const unsigned short* Abase = Apack + (size_t)c * (256 * LDA);
  const unsigned short* Bbase = BT + (size_t)(kt0 * 2) * LDBT;
  // Per-lane A fragment base: row = w*64 + fi*16 + llo, elem = kk + kf*32 + lhi*8.
  // Full wave: 16 rows x 64 contiguous bytes each -> 16 fully-used cache lines.
  const unsigned short* Arow = Abase + (size_t)(w * 64 + llo) * LDA + lhi * 8;

  f32x4 acc[4][8];
#pragma unroll
  for (int i = 0; i < 4; ++i)
#pragma unroll
    for (int j = 0; j < 8; ++j) {
      f32x4 z = {0.f, 0.f, 0.f, 0.f};
      acc[i][j] = z;
    }

  // Prologue: stage B tile 0 into Bs[0] (16 x 1KB chunks; wave w does 4)
#pragma unroll
  for (int i = 0; i < 4; ++i) {
    int row0 = (w * 4 + i) * 8;
    async_copy16(&Bs[0][row0 * 64], Bbase + (size_t)(row0 + lr) * LDBT + lcs);
  }
  __syncthreads();

  int cur = 0;
  for (int t = 0; t < 8; ++t) {
    const int kk = t * 64;
    // Issue A fragment loads for this tile up front (latency overlaps staging
    // issue + lgkm wait before first MFMA).
    bf16x8 af[2][4];
#pragma unroll
    for (int kf = 0; kf < 2; ++kf)
#pragma unroll
      for (int fi = 0; fi < 4; ++fi)
        af[kf][fi] = *(const bf16x8*)(Arow + (size_t)fi * 16 * LDA + kk + kf * 32);

    // Issue next B tile's staging loads BEFORE compute; the vmcnt(0) drain at
    // the barrier below then lands ~64 MFMAs later (hidden).
    if (t < 7) {
      const int kn = kk + 64;
#pragma unroll
      for (int i = 0; i < 4; ++i) {
        int row0 = (w * 4 + i) * 8;
        async_copy16(&Bs[cur ^ 1][row0 * 64],
                     Bbase + (size_t)(row0 + lr) * LDBT + kn + lcs);
      }
    }

#pragma unroll
    for (int kf = 0; kf < 2; ++kf) {
      const int slotbase = kf * 4 + lhi;
      const int soff = (slotbase ^ (llo & 7)) * 8;  // swizzled chunk -> elem off
      bf16x8 bfr[8];
#pragma unroll
      for (int fj = 0; fj < 8; ++fj)
        bfr[fj] = *(const bf16x8*)&Bs[cur][(fj * 16 + llo) * 64 + soff];
#pragma unroll
      for (int fi = 0; fi < 4; ++fi)
#pragma unroll
        for (int fj = 0; fj < 8; ++fj)
          acc[fi][fj] = __builtin_amdgcn_mfma_f32_16x16x32_bf16(
              af[kf][fi], bfr[fj], acc[fi][fj], 0, 0, 0);
    }
    __syncthreads();   // drain (cheap now) + barrier; Bs[cur^1] ready
    cur ^= 1;
  }

  // Epilogue: y_partial[col] = sum over this wave's a-rows of E1 (*) tmp
  // col = fj*16 + llo; even col -> Re(tmp), odd -> Im(tmp) for k = kt0 + col/2
#pragma unroll
  for (int fj = 0; fj < 8; ++fj) {
    const int col = fj * 16 + llo;
    const int k = kt0 + (col >> 1);
    const float sign = (col & 1) ? 1.f : -1.f;
    float sum = 0.f;
    const unsigned int* e1base = E1tab + (size_t)k * 256 + w * 64 + lhi * 4;
#pragma unroll
    for (int fi = 0; fi < 4; ++fi) {
      uint4 e4 = *(const uint4*)(e1base + fi * 16);
      unsigned int ev[4] = {e4.x, e4.y, e4.z, e4.w};
#pragma unroll
      for (int r = 0; r < 4; ++r) {
        float v = acc[fi][fj][r];             // this comp at (a, k)
        float p = __shfl_xor(v, 1, 64);       // partner comp at same (a, k)
        float er = bf2f(ev[r] & 0xFFFFu);
        float ei = bf2f(ev[r] >> 16);
        // even col: Re(y) += er*tr - ei*ti ; odd col: Im(y) += er*ti + ei*tr
        sum += er * v + sign * ei * p;
      }
    }
    sum += __shfl_xor(sum, 16, 64);
    sum += __shfl_xor(sum, 32, 64);
    if (lhi == 0) wavecol[w][col] = sum;
  }
  __syncthreads();
  if (tid < 128) {
    float sv = wavecol[0][tid] + wavecol[1][tid] + wavecol[2][tid] + wavecol[3][tid];
    int k = kt0 + (tid >> 1);
    out[((size_t)c * NKTOT + k) * 2 + (tid & 1)] = sv * wvec[k & 511];
  }
}

extern "C" void kernel_launch(void* const* d_in, const int* in_sizes, int n_in,
                              void* d_out, int out_size, void* d_ws, size_t ws_size,
                              hipStream_t stream) {
  const float* input_r = (const float*)d_in[0];  // (256,256,2)
  const float* C_r     = (const float*)d_in[1];  // (8,256,256,2)
  const float* wvec    = (const float*)d_in[2];  // (512,)
  const float* angle   = (const float*)d_in[3];  // (17408,2)
  float* out = (float*)d_out;                    // (8,17408,2)

  // workspace layout: A' (2MB) | B'T (34MB) | E1tab (17MB)  => ~53MB
  unsigned short* Apack = (unsigned short*)d_ws;
  unsigned short* BT    = (unsigned short*)((char*)d_ws + (size_t)2097152);
  unsigned int*   E1tab = (unsigned int*)((char*)d_ws + (size_t)2097152 + 35651584);

  pack_a<<<2048, 256, 0, stream>>>(input_r, C_r, Apack);
  pack_be<<<NKTOT / 4, 256, 0, stream>>>(angle, BT, E1tab);
  gemm_fused<<<8 * NBLK_K, 256, 0, stream>>>(Apack, BT, E1tab, wvec, out);
}

// Round 2
// 177.636 us; speedup vs baseline: 1.6760x; 1.6760x over previous
//
#include <hip/hip_runtime.h>
#include <hip/hip_bf16.h>
#include <stdint.h>

// y[c,k] = sum_{a,b} E1[k,a] * Xc[c,a,b] * E2[k,b],  Xc = C*x, E = exp(i*angle*g)
// Stage 1 (MFMA): tmp[a, 2k+comp] = A'[a,:] @ B'[:, 2k+comp]
//   A' = [Re(Xc) | Im(Xc)]  (256 x 512)
//   B'[b,2k]=Er, B'[256+b,2k]=-Ei, B'[b,2k+1]=Ei, B'[256+b,2k+1]=Er
// Stage 2 (epilogue): y[c,k] = sum_a E1[k,a] (*) tmp[a,k]  (complex), * w[k%512]
//
// R2 (fixed R1): 2-phase prefetch + A-direct-from-global, at the RIGHT
// register budget.
//  - __launch_bounds__(256, 2): unified VGPR+AGPR cap 256/wave. R1's (256,3)
//    capped at ~170 < the ~236 this kernel needs -> in-loop acc spills
//    (WRITE_SIZE 1MB -> 464MB). 3 waves/SIMD is arithmetically impossible
//    with a 128-reg accumulator; don't ask for it.
//  - A fragments loaded per-kf-phase (16 regs live, not 32): peak pressure
//    ~252 <= 256, no spill.
//  - B tile double-buffered in LDS; stage(t+1) issued BEFORE compute(t),
//    single __syncthreads() per K-step. The vmcnt(0) drain at the barrier
//    lands ~64 MFMAs after load issue -> latency hidden.
//  - Bs keeps the chunk-XOR swizzle (slot = chunk ^ (row&7)): fragment
//    ds_read_b128s bank-balanced (conflicts 0 in R0/R1).

#define NKTOT 17408
#define NBLK_K 272   // 17408 / 64
#define LDA 512
#define LDBT 512

typedef short bf16x8 __attribute__((ext_vector_type(8)));
typedef float f32x4 __attribute__((ext_vector_type(4)));

__device__ __forceinline__ unsigned short f2bf(float f) {
  unsigned int u = __builtin_bit_cast(unsigned int, f);
  u += 0x7FFFu + ((u >> 16) & 1u);
  return (unsigned short)(u >> 16);
}
__device__ __forceinline__ float bf2f(unsigned int lo16) {
  return __builtin_bit_cast(float, lo16 << 16);
}

__device__ __forceinline__ void async_copy16(void* lds, const void* g) {
  __builtin_amdgcn_global_load_lds(
      (const __attribute__((address_space(1))) unsigned int*)g,
      (__attribute__((address_space(3))) unsigned int*)lds, 16, 0, 0);
}

__global__ __launch_bounds__(256) void pack_a(
    const float* __restrict__ input_r, const float* __restrict__ C_r,
    unsigned short* __restrict__ Apack)
{
  int tid = blockIdx.x * 256 + threadIdx.x;  // 0 .. 8*256*256-1
  int b = tid & 255;
  int a = (tid >> 8) & 255;
  int c = tid >> 16;
  float xr = input_r[(a * 256 + b) * 2 + 0];
  float xi = input_r[(a * 256 + b) * 2 + 1];
  size_t ci0 = ((size_t)(c * 256 + a) * 256 + b) * 2;
  float cr = C_r[ci0 + 0];
  float ci = C_r[ci0 + 1];
  float re = cr * xr - ci * xi;
  float im = cr * xi + ci * xr;
  size_t base = (size_t)c * (256 * LDA) + (size_t)a * LDA;
  Apack[base + b] = f2bf(re);
  Apack[base + 256 + b] = f2bf(im);
}

// 4 k per block, 64 lanes per k, 4 consecutive b per lane -> 8B/16B wide stores
__global__ __launch_bounds__(256) void pack_be(
    const float* __restrict__ angle,
    unsigned short* __restrict__ BT, unsigned int* __restrict__ E1tab)
{
  int tid = threadIdx.x;
  int k = blockIdx.x * 4 + (tid >> 6);   // 0..17407
  int b0 = (tid & 63) * 4;               // 0,4,..,252
  float s = angle[k * 2 + 0];
  float t = angle[k * 2 + 1];
  unsigned short c2[4], s2[4], c1[4], s1[4];
#pragma unroll
  for (int j = 0; j < 4; ++j) {
    float g = (float)(b0 + j - 128);
    float sn, cs;
    __sincosf(t * g, &sn, &cs);
    c2[j] = f2bf(cs);
    s2[j] = f2bf(sn);
    __sincosf(s * g, &sn, &cs);
    c1[j] = f2bf(cs);
    s1[j] = f2bf(sn);
  }
  size_t r0 = (size_t)(2 * k) * LDBT;
  ushort4 v;
  v = make_ushort4(c2[0], c2[1], c2[2], c2[3]);
  *(ushort4*)&BT[r0 + b0] = v;
  v = make_ushort4((unsigned short)(s2[0] ^ 0x8000u), (unsigned short)(s2[1] ^ 0x8000u),
                   (unsigned short)(s2[2] ^ 0x8000u), (unsigned short)(s2[3] ^ 0x8000u));
  *(ushort4*)&BT[r0 + 256 + b0] = v;
  v = make_ushort4(s2[0], s2[1], s2[2], s2[3]);
  *(ushort4*)&BT[r0 + LDBT + b0] = v;
  v = make_ushort4(c2[0], c2[1], c2[2], c2[3]);
  *(ushort4*)&BT[r0 + LDBT + 256 + b0] = v;
  uint4 e;
  e.x = (unsigned int)c1[0] | ((unsigned int)s1[0] << 16);
  e.y = (unsigned int)c1[1] | ((unsigned int)s1[1] << 16);
  e.z = (unsigned int)c1[2] | ((unsigned int)s1[2] << 16);
  e.w = (unsigned int)c1[3] | ((unsigned int)s1[3] << 16);
  *(uint4*)&E1tab[k * 256 + b0] = e;
}

__global__ __launch_bounds__(256, 2) void gemm_fused(
    const unsigned short* __restrict__ Apack,
    const unsigned short* __restrict__ BT,
    const unsigned int* __restrict__ E1tab,
    const float* __restrict__ wvec,
    float* __restrict__ out)
{
  __shared__ unsigned short Bs[2][128 * 64];  // 2 x 16 KB, double-buffered
  __shared__ float wavecol[4][128];

  // XCD-aware decode: bx%8 == kt%8 keeps all 8 c-blocks of one kt on the same
  // XCD so its L2 serves B/E1 tiles (and all 8 c-slices of A, 2MB) once.
  const int bx = blockIdx.x;
  const int c = (bx >> 3) & 7;
  const int kt = (bx >> 6) * 8 + (bx & 7);
  const int kt0 = kt * 64;
  const int tid = threadIdx.x;
  const int w = tid >> 6;
  const int l = tid & 63;
  const int lhi = l >> 4;   // 0..3
  const int llo = l & 15;
  const int lr = l >> 3;                       // staging: row within 8-row chunk
  const int lcs = ((l & 7) ^ (l >> 3)) * 8;    // staging: swizzled source chunk

  const unsigned short* Abase = Apack + (size_t)c * (256 * LDA);
  const unsigned short* Bbase = BT + (size_t)(kt0 * 2) * LDBT;
  // Per-lane A fragment base: row = w*64 + fi*16 + llo, elem = kk + kf*32 + lhi*8.
  // Full wave: 16 rows x 64 contiguous bytes each -> 16 fully-used cache lines.
  const unsigned short* Arow = Abase + (size_t)(w * 64 + llo) * LDA + lhi * 8;

  f32x4 acc[4][8];
#pragma unroll
  for (int i = 0; i < 4; ++i)
#pragma unroll
    for (int j = 0; j < 8; ++j) {
      f32x4 z = {0.f, 0.f, 0.f, 0.f};
      acc[i][j] = z;
    }

  // Prologue: stage B tile 0 into Bs[0] (16 x 1KB chunks; wave w does 4)
#pragma unroll
  for (int i = 0; i < 4; ++i) {
    int row0 = (w * 4 + i) * 8;
    async_copy16(&Bs[0][row0 * 64], Bbase + (size_t)(row0 + lr) * LDBT + lcs);
  }
  __syncthreads();

  int cur = 0;
  for (int t = 0; t < 8; ++t) {
    const int kk = t * 64;
    // Issue next B tile's staging loads BEFORE compute; the vmcnt(0) drain at
    // the barrier below then lands ~64 MFMAs later (hidden).
    if (t < 7) {
      const int kn = kk + 64;
#pragma unroll
      for (int i = 0; i < 4; ++i) {
        int row0 = (w * 4 + i) * 8;
        async_copy16(&Bs[cur ^ 1][row0 * 64],
                     Bbase + (size_t)(row0 + lr) * LDBT + kn + lcs);
      }
    }

#pragma unroll
    for (int kf = 0; kf < 2; ++kf) {
      // A fragments per kf-phase: 16 regs live (not 32) keeps peak unified
      // pressure ~252 <= 256-reg cap of (256,2). L2-hit latency overlaps the
      // 8 ds_read_b128s below + other wave's MFMAs.
      bf16x8 af[4];
#pragma unroll
      for (int fi = 0; fi < 4; ++fi)
        af[fi] = *(const bf16x8*)(Arow + (size_t)fi * 16 * LDA + kk + kf * 32);

      const int slotbase = kf * 4 + lhi;
      const int soff = (slotbase ^ (llo & 7)) * 8;  // swizzled chunk -> elem off
      bf16x8 bfr[8];
#pragma unroll
      for (int fj = 0; fj < 8; ++fj)
        bfr[fj] = *(const bf16x8*)&Bs[cur][(fj * 16 + llo) * 64 + soff];
#pragma unroll
      for (int fi = 0; fi < 4; ++fi)
#pragma unroll
        for (int fj = 0; fj < 8; ++fj)
          acc[fi][fj] = __builtin_amdgcn_mfma_f32_16x16x32_bf16(
              af[fi], bfr[fj], acc[fi][fj], 0, 0, 0);
    }
    __syncthreads();   // drain (hidden now) + barrier; Bs[cur^1] ready
    cur ^= 1;
  }

  // Epilogue: y_partial[col] = sum over this wave's a-rows of E1 (*) tmp
  // col = fj*16 + llo; even col -> Re(tmp), odd -> Im(tmp) for k = kt0 + col/2
#pragma unroll
  for (int fj = 0; fj < 8; ++fj) {
    const int col = fj * 16 + llo;
    const int k = kt0 + (col >> 1);
    const float sign = (col & 1) ? 1.f : -1.f;
    float sum = 0.f;
    const unsigned int* e1base = E1tab + (size_t)k * 256 + w * 64 + lhi * 4;
#pragma unroll
    for (int fi = 0; fi < 4; ++fi) {
      uint4 e4 = *(const uint4*)(e1base + fi * 16);
      unsigned int ev[4] = {e4.x, e4.y, e4.z, e4.w};
#pragma unroll
      for (int r = 0; r < 4; ++r) {
        float v = acc[fi][fj][r];             // this comp at (a, k)
        float p = __shfl_xor(v, 1, 64);       // partner comp at same (a, k)
        float er = bf2f(ev[r] & 0xFFFFu);
        float ei = bf2f(ev[r] >> 16);
        // even col: Re(y) += er*tr - ei*ti ; odd col: Im(y) += er*ti + ei*tr
        sum += er * v + sign * ei * p;
      }
    }
    sum += __shfl_xor(sum, 16, 64);
    sum += __shfl_xor(sum, 32, 64);
    if (lhi == 0) wavecol[w][col] = sum;
  }
  __syncthreads();
  if (tid < 128) {
    float sv = wavecol[0][tid] + wavecol[1][tid] + wavecol[2][tid] + wavecol[3][tid];
    int k = kt0 + (tid >> 1);
    out[((size_t)c * NKTOT + k) * 2 + (tid & 1)] = sv * wvec[k & 511];
  }
}

extern "C" void kernel_launch(void* const* d_in, const int* in_sizes, int n_in,
                              void* d_out, int out_size, void* d_ws, size_t ws_size,
                              hipStream_t stream) {
  const float* input_r = (const float*)d_in[0];  // (256,256,2)
  const float* C_r     = (const float*)d_in[1];  // (8,256,256,2)
  const float* wvec    = (const float*)d_in[2];  // (512,)
  const float* angle   = (const float*)d_in[3];  // (17408,2)
  float* out = (float*)d_out;                    // (8,17408,2)

  // workspace layout: A' (2MB) | B'T (34MB) | E1tab (17MB)  => ~53MB
  unsigned short* Apack = (unsigned short*)d_ws;
  unsigned short* BT    = (unsigned short*)((char*)d_ws + (size_t)2097152);
  unsigned int*   E1tab = (unsigned int*)((char*)d_ws + (size_t)2097152 + 35651584);

  pack_a<<<2048, 256, 0, stream>>>(input_r, C_r, Apack);
  pack_be<<<NKTOT / 4, 256, 0, stream>>>(angle, BT, E1tab);
  gemm_fused<<<8 * NBLK_K, 256, 0, stream>>>(Apack, BT, E1tab, wvec, out);
}

// Round 3
// 168.555 us; speedup vs baseline: 1.7663x; 1.0539x over previous
//
#include <hip/hip_runtime.h>
#include <hip/hip_bf16.h>
#include <stdint.h>

// y[c,k] = sum_{a,b} E1[k,a] * Xc[c,a,b] * E2[k,b],  Xc = C*x, E = exp(i*angle*g)
// Stage 1 (MFMA): tmp[a, 2k+comp] = A'[a,:] @ B'[:, 2k+comp]
//   A' = [Re(Xc) | Im(Xc)]  (256 x 512)
//   B'[b,2k]=Er, B'[256+b,2k]=-Ei, B'[b,2k+1]=Ei, B'[256+b,2k+1]=Er
// Stage 2 (epilogue): y[c,k] = sum_a E1[k,a] (*) tmp[a,k]  (complex), * w[k%512]
//
// R3: 8-phase-template port (m201 recipe). BM=256 x BN=256 (128 k) x BK=64,
// 512 thr / 8 waves (2M x 4N), wave tile 128x64, acc[8][4]. A+B double-buffered
// in LDS (128 KB), 1 block/CU. Per K-tile: 4 phases, each
//   {ds_read operand-half || stage quota -> sched_barrier(0) -> s_barrier ->
//    setprio(1) + 16 MFMA + setprio(0) -> s_barrier}
// zigzag quadrants Q00->Q01->Q11->Q10 so each phase loads ONE new half
// (24 ds_read_b128/wave/tile = minimum). Staging for t+1 issued phases 0-2;
// the ONLY vmcnt drain is the tile-end __syncthreads (~1000 cyc after issue,
// hidden). R2's lesson: never put per-lane VMEM loads after global_load_lds
// in the same phase (shared in-order vmcnt forces a full drain) -> A is back
// in LDS. Correctness relies only on the full-fence __syncthreads at the
// swap (same safety class as R0); raw barriers/setprio are scheduling-only.

#define NKTOT 17408
#define NBLK_K2 136  // 17408 / 128
#define LDA 512
#define LDBT 512

typedef short bf16x8 __attribute__((ext_vector_type(8)));
typedef float f32x4 __attribute__((ext_vector_type(4)));

__device__ __forceinline__ unsigned short f2bf(float f) {
  unsigned int u = __builtin_bit_cast(unsigned int, f);
  u += 0x7FFFu + ((u >> 16) & 1u);
  return (unsigned short)(u >> 16);
}
__device__ __forceinline__ float bf2f(unsigned int lo16) {
  return __builtin_bit_cast(float, lo16 << 16);
}

__device__ __forceinline__ void async_copy16(void* lds, const void* g) {
  __builtin_amdgcn_global_load_lds(
      (const __attribute__((address_space(1))) unsigned int*)g,
      (__attribute__((address_space(3))) unsigned int*)lds, 16, 0, 0);
}

__global__ __launch_bounds__(256) void pack_a(
    const float* __restrict__ input_r, const float* __restrict__ C_r,
    unsigned short* __restrict__ Apack)
{
  int tid = blockIdx.x * 256 + threadIdx.x;  // 0 .. 8*256*256-1
  int b = tid & 255;
  int a = (tid >> 8) & 255;
  int c = tid >> 16;
  float xr = input_r[(a * 256 + b) * 2 + 0];
  float xi = input_r[(a * 256 + b) * 2 + 1];
  size_t ci0 = ((size_t)(c * 256 + a) * 256 + b) * 2;
  float cr = C_r[ci0 + 0];
  float ci = C_r[ci0 + 1];
  float re = cr * xr - ci * xi;
  float im = cr * xi + ci * xr;
  size_t base = (size_t)c * (256 * LDA) + (size_t)a * LDA;
  Apack[base + b] = f2bf(re);
  Apack[base + 256 + b] = f2bf(im);
}

// 4 k per block, 64 lanes per k, 4 consecutive b per lane -> 8B/16B wide stores
__global__ __launch_bounds__(256) void pack_be(
    const float* __restrict__ angle,
    unsigned short* __restrict__ BT, unsigned int* __restrict__ E1tab)
{
  int tid = threadIdx.x;
  int k = blockIdx.x * 4 + (tid >> 6);   // 0..17407
  int b0 = (tid & 63) * 4;               // 0,4,..,252
  float s = angle[k * 2 + 0];
  float t = angle[k * 2 + 1];
  unsigned short c2[4], s2[4], c1[4], s1[4];
#pragma unroll
  for (int j = 0; j < 4; ++j) {
    float g = (float)(b0 + j - 128);
    float sn, cs;
    __sincosf(t * g, &sn, &cs);
    c2[j] = f2bf(cs);
    s2[j] = f2bf(sn);
    __sincosf(s * g, &sn, &cs);
    c1[j] = f2bf(cs);
    s1[j] = f2bf(sn);
  }
  size_t r0 = (size_t)(2 * k) * LDBT;
  ushort4 v;
  v = make_ushort4(c2[0], c2[1], c2[2], c2[3]);
  *(ushort4*)&BT[r0 + b0] = v;
  v = make_ushort4((unsigned short)(s2[0] ^ 0x8000u), (unsigned short)(s2[1] ^ 0x8000u),
                   (unsigned short)(s2[2] ^ 0x8000u), (unsigned short)(s2[3] ^ 0x8000u));
  *(ushort4*)&BT[r0 + 256 + b0] = v;
  v = make_ushort4(s2[0], s2[1], s2[2], s2[3]);
  *(ushort4*)&BT[r0 + LDBT + b0] = v;
  v = make_ushort4(c2[0], c2[1], c2[2], c2[3]);
  *(ushort4*)&BT[r0 + LDBT + 256 + b0] = v;
  uint4 e;
  e.x = (unsigned int)c1[0] | ((unsigned int)s1[0] << 16);
  e.y = (unsigned int)c1[1] | ((unsigned int)s1[1] << 16);
  e.z = (unsigned int)c1[2] | ((unsigned int)s1[2] << 16);
  e.w = (unsigned int)c1[3] | ((unsigned int)s1[3] << 16);
  *(uint4*)&E1tab[k * 256 + b0] = e;
}

// ---- gemm helpers -----------------------------------------------------------

template<int QM>
__device__ __forceinline__ void load_ahalf(bf16x8 (&af)[2][4],
    const unsigned short* Ac, int arow0, int sl0) {
#pragma unroll
  for (int kh = 0; kh < 2; ++kh)
#pragma unroll
    for (int ii = 0; ii < 4; ++ii)
      af[kh][ii] = *(const bf16x8*)
          &Ac[(arow0 + QM * 64 + ii * 16) * 64 + (sl0 ^ (kh * 4)) * 8];
}

template<int QN>
__device__ __forceinline__ void load_bhalf(bf16x8 (&bf)[2][2],
    const unsigned short* Bc, int brow0, int sl0) {
#pragma unroll
  for (int kh = 0; kh < 2; ++kh)
#pragma unroll
    for (int jj = 0; jj < 2; ++jj)
      bf[kh][jj] = *(const bf16x8*)
          &Bc[(brow0 + QN * 32 + jj * 16) * 64 + (sl0 ^ (kh * 4)) * 8];
}

template<int QM, int QN>
__device__ __forceinline__ void mfma_quad(f32x4 (&acc)[8][4],
    const bf16x8 (&af)[2][4], const bf16x8 (&bf)[2][2]) {
#pragma unroll
  for (int kh = 0; kh < 2; ++kh)
#pragma unroll
    for (int ii = 0; ii < 4; ++ii)
#pragma unroll
      for (int jj = 0; jj < 2; ++jj)
        acc[QM * 4 + ii][QN * 2 + jj] = __builtin_amdgcn_mfma_f32_16x16x32_bf16(
            af[kh][ii], bf[kh][jj], acc[QM * 4 + ii][QN * 2 + jj], 0, 0, 0);
}

// wave w stages chunk i (rows (w*4+i)*8 .. +7) with the chunk-XOR swizzle:
// LDS dest linear (gload_lds requirement), global source chunk permuted.
__device__ __forceinline__ void stage_chunk(unsigned short* dst,
    const unsigned short* src_base, int w, int i, int lr, int lcs, int kk) {
  int row0 = (w * 4 + i) * 8;
  async_copy16(&dst[row0 * 64], src_base + (size_t)(row0 + lr) * 512 + kk + lcs);
}

__global__ __launch_bounds__(512, 2) void gemm_fused(
    const unsigned short* __restrict__ Apack,
    const unsigned short* __restrict__ BT,
    const unsigned int* __restrict__ E1tab,
    const float* __restrict__ wvec,
    float* __restrict__ out)
{
  __shared__ unsigned short As[2][256 * 64];   // 2 x 32 KB
  __shared__ unsigned short Bs2[2][256 * 64];  // 2 x 32 KB
  __shared__ float wavecol[2][256];            // 2 KB

  // XCD-aware decode: bx%8 == ktile%8 keeps all 8 c-blocks of one ktile on the
  // same XCD (shared BT/E1 slices served from one L2). 1088 = 17*64, bijective.
  const int bx = blockIdx.x;
  const int c = (bx >> 3) & 7;
  const int ktile = (bx >> 6) * 8 + (bx & 7);   // 0..135
  const int kt0 = ktile * 128;                  // k offset (128 k per block)
  const int tid = threadIdx.x;
  const int w = tid >> 6;       // 0..7
  const int wr = w >> 2;        // 0..1  M-half (rows wr*128..)
  const int wc = w & 3;         // 0..3  N-quarter (cols wc*64..)
  const int l = tid & 63;
  const int lhi = l >> 4;       // 0..3
  const int llo = l & 15;
  const int lr = l >> 3;                      // staging: row within 8-row chunk
  const int lcs = ((l & 7) ^ lr) * 8;         // staging: swizzled source chunk

  const unsigned short* Abase = Apack + (size_t)c * (256 * LDA);
  const unsigned short* Bbase = BT + (size_t)(ktile * 256) * LDBT;

  // LDS fragment addressing: row-local layout [row][slot*8], slot=(kh*4+lhi)^(row&7)
  const int sl0 = lhi ^ (llo & 7);   // kh=0 slot; kh=1 slot = sl0^4
  const int arow0 = wr * 128 + llo;
  const int brow0 = wc * 64 + llo;

  f32x4 acc[8][4];
#pragma unroll
  for (int i = 0; i < 8; ++i)
#pragma unroll
    for (int j = 0; j < 4; ++j) {
      f32x4 z = {0.f, 0.f, 0.f, 0.f};
      acc[i][j] = z;
    }

  // Prologue: stage tile 0 (8 chunks/wave: 4 A + 4 B)
#pragma unroll
  for (int i = 0; i < 4; ++i) {
    stage_chunk(&As[0][0], Abase, w, i, lr, lcs, 0);
    stage_chunk(&Bs2[0][0], Bbase, w, i, lr, lcs, 0);
  }
  __syncthreads();

#pragma unroll 2
  for (int t = 0; t < 8; ++t) {
    const int cu = t & 1;
    const unsigned short* Ac = As[cu];
    const unsigned short* Bc = Bs2[cu];
    unsigned short* An = As[cu ^ 1];
    unsigned short* Bn = Bs2[cu ^ 1];
    const int kn = (t + 1) * 64;
    const bool pf = (t < 7);

    bf16x8 af[2][4], bfA[2][2], bfB[2][2];

    // ---- phase 0: read A-half0 + B-half0; stage A0,A1,B0; MFMA Q(0,0)
    load_ahalf<0>(af, Ac, arow0, sl0);
    load_bhalf<0>(bfA, Bc, brow0, sl0);
    if (pf) {
      stage_chunk(An, Abase, w, 0, lr, lcs, kn);
      stage_chunk(An, Abase, w, 1, lr, lcs, kn);
      stage_chunk(Bn, Bbase, w, 0, lr, lcs, kn);
    }
    __builtin_amdgcn_sched_barrier(0);
    __builtin_amdgcn_s_barrier();
    __builtin_amdgcn_s_setprio(1);
    mfma_quad<0, 0>(acc, af, bfA);
    __builtin_amdgcn_s_setprio(0);
    __builtin_amdgcn_s_barrier();

    // ---- phase 1: read B-half1 (reuse A-half0); stage A2,A3,B1; MFMA Q(0,1)
    load_bhalf<1>(bfB, Bc, brow0, sl0);
    if (pf) {
      stage_chunk(An, Abase, w, 2, lr, lcs, kn);
      stage_chunk(An, Abase, w, 3, lr, lcs, kn);
      stage_chunk(Bn, Bbase, w, 1, lr, lcs, kn);
    }
    __builtin_amdgcn_sched_barrier(0);
    __builtin_amdgcn_s_barrier();
    __builtin_amdgcn_s_setprio(1);
    mfma_quad<0, 1>(acc, af, bfB);
    __builtin_amdgcn_s_setprio(0);
    __builtin_amdgcn_s_barrier();

    // ---- phase 2: read A-half1 (reuse B-half1); stage B2,B3; MFMA Q(1,1)
    load_ahalf<1>(af, Ac, arow0, sl0);
    if (pf) {
      stage_chunk(Bn, Bbase, w, 2, lr, lcs, kn);
      stage_chunk(Bn, Bbase, w, 3, lr, lcs, kn);
    }
    __builtin_amdgcn_sched_barrier(0);
    __builtin_amdgcn_s_barrier();
    __builtin_amdgcn_s_setprio(1);
    mfma_quad<1, 1>(acc, af, bfB);
    __builtin_amdgcn_s_setprio(0);
    __builtin_amdgcn_s_barrier();

    // ---- phase 3: no reads (reuse A-half1 + B-half0); MFMA Q(1,0)
    __builtin_amdgcn_s_setprio(1);
    mfma_quad<1, 0>(acc, af, bfA);
    __builtin_amdgcn_s_setprio(0);
    // Tile end: full fence + vmcnt drain (staging issued phases 0-2, ~1000 cyc
    // old -> cheap) + swap barrier. This is the ONLY correctness barrier.
    __syncthreads();
  }

  // Epilogue: y_partial[col] = sum over this wave's 128 a-rows of E1 (*) tmp
  // col = wc*64 + fj*16 + llo; even col -> Re(tmp), odd -> Im, k = kt0 + col/2
#pragma unroll
  for (int fj = 0; fj < 4; ++fj) {
    const int col = wc * 64 + fj * 16 + llo;
    const int k = kt0 + (col >> 1);
    const float sign = (col & 1) ? 1.f : -1.f;
    float sum = 0.f;
    const unsigned int* e1base = E1tab + (size_t)k * 256 + wr * 128 + lhi * 4;
#pragma unroll
    for (int fi = 0; fi < 8; ++fi) {
      uint4 e4 = *(const uint4*)(e1base + fi * 16);
      unsigned int ev[4] = {e4.x, e4.y, e4.z, e4.w};
#pragma unroll
      for (int r = 0; r < 4; ++r) {
        float v = acc[fi][fj][r];             // this comp at (a, k)
        float p = __shfl_xor(v, 1, 64);       // partner comp at same (a, k)
        float er = bf2f(ev[r] & 0xFFFFu);
        float ei = bf2f(ev[r] >> 16);
        // even col: Re(y) += er*tr - ei*ti ; odd col: Im(y) += er*ti + ei*tr
        sum += er * v + sign * ei * p;
      }
    }
    sum += __shfl_xor(sum, 16, 64);
    sum += __shfl_xor(sum, 32, 64);
    if (lhi == 0) wavecol[wr][col] = sum;
  }
  __syncthreads();
  if (tid < 256) {
    float sv = wavecol[0][tid] + wavecol[1][tid];
    int k = kt0 + (tid >> 1);
    out[((size_t)c * NKTOT + k) * 2 + (tid & 1)] = sv * wvec[k & 511];
  }
}

extern "C" void kernel_launch(void* const* d_in, const int* in_sizes, int n_in,
                              void* d_out, int out_size, void* d_ws, size_t ws_size,
                              hipStream_t stream) {
  const float* input_r = (const float*)d_in[0];  // (256,256,2)
  const float* C_r     = (const float*)d_in[1];  // (8,256,256,2)
  const float* wvec    = (const float*)d_in[2];  // (512,)
  const float* angle   = (const float*)d_in[3];  // (17408,2)
  float* out = (float*)d_out;                    // (8,17408,2)

  // workspace layout: A' (2MB) | B'T (34MB) | E1tab (17MB)  => ~55MB
  unsigned short* Apack = (unsigned short*)d_ws;
  unsigned short* BT    = (unsigned short*)((char*)d_ws + (size_t)2097152);
  unsigned int*   E1tab = (unsigned int*)((char*)d_ws + (size_t)2097152 + 35651584);

  pack_a<<<2048, 256, 0, stream>>>(input_r, C_r, Apack);
  pack_be<<<NKTOT / 4, 256, 0, stream>>>(angle, BT, E1tab);
  gemm_fused<<<8 * NBLK_K2, 512, 0, stream>>>(Apack, BT, E1tab, wvec, out);
}